// Round 13
// baseline (100.048 us; speedup 1.0000x reference)
//
#include <hip/hip_runtime.h>
#include <math.h>

// Problem constants (from reference): B=8, C=32, F=32, K=3, H=W=32
#define NB 8
#define NC 32
#define NF 32
#define NH 32
#define NW 32
#define NQ 9
#define FSPLIT 8   // f-quads per (b,y)
#define FPB 4      // f per block = ONE PER WAVE
#define TSX 36     // padded LDS row stride (floats): 144B rows, 16B-aligned

typedef float f2 __attribute__((ext_vector_type(2)));

// v11: channels-on-lanes (v10) with the w-feed fixed.
// v10 post-mortem: mapping removed coeff/SGPR fat but added 144 strided
// per-eval ds_read_b32 on the Horner critical path (~11us LDS pipe).
// v11 makes each half-wave's pixels CONTIGUOUS (sl=0: cols 0-15, sl=1:
// cols 16-31): per (pixel-group g, row qi) one lane needs a 10-float
// contiguous window -> b128+b128+b64 (16B-aligned, stride TSX=36),
// HOISTED out of the eval loop: 18 wide reads/wave vs 144 scalar, 48
// evals per window. Coeffs stay per-lane VMEM on the contiguous c-axis
// (f2 x5 per q, VGPR-destined, no splat movs, no SGPR waits). Pixels in
// 2 groups of 8: acc[8]+w[10]+~30 coeff regs ~= 58 VGPR < 64 cap (the
// 3x-measured spill cliff). qi runtime-looped; qj/j static (no runtime
// register indexing -> no scratch). Butterfly c-sum + direct store: no
// atomics, no out-memset. Grid 2048 = 8 blocks/CU, LDS 13.8KB.
__global__ __launch_bounds__(256, 8) void ka_conv_rational_kernel(
    const float* __restrict__ x,     // [B, C, H, W]
    const float* __restrict__ nums,  // [F*Q*C, 6]
    const float* __restrict__ dens,  // [F*Q*C, 4]
    float* __restrict__ out)         // [B, F, H, W]
{
    __shared__ float xt[NC][3][TSX]; // 13,824 B

    const int t   = threadIdx.x;
    const int bid = blockIdx.x;        // 0..2047 = (b, y, fq)
    const int fq  = bid & (FSPLIT - 1);
    const int y   = (bid >> 3) & (NH - 1);
    const int b   = bid >> 8;

    // ---- stage x[b, all c, y-1..y+1, all cols], zero-padded cols 0/33.
    // Coalesced: consecutive threads -> consecutive cols of 128B rows.
#pragma unroll
    for (int i = 0; i < 12; ++i) {
        int e   = t + i * 256;          // 3072 = 32c * 3r * 32col
        int cc  = e / 96;
        int rem = e - cc * 96;
        int rr  = rem >> 5;
        int col = rem & 31;
        int gy  = y - 1 + rr;
        float v = (gy >= 0 && gy < NH)
                      ? x[(((size_t)b * NC + cc) * NH + gy) * NW + col]
                      : 0.f;
        xt[cc][rr][col + 1] = v;
    }
    if (t < 96) {
        int cc = t / 3, rr = t - (t / 3) * 3;
        xt[cc][rr][0] = 0.f;
    } else if (t >= 128 && t < 224) {
        int u = t - 128;
        int cc = u / 3, rr = u - (u / 3) * 3;
        xt[cc][rr][33] = 0.f;
    }
    __syncthreads(); // only barrier

    const int lane = t & 63;
    const int c    = lane & 31; // this lane's channel
    const int sl   = lane >> 5; // pixel half: cols sl*16 .. sl*16+15
    const int wv   = t >> 6;    // 0..3
    const int f    = fq * FPB + wv;

    // per-lane coefficient bases (q advances by NC rows = 768B / 512B)
    const float* __restrict__ nb = nums + ((size_t)f * NQ * NC + c) * 6;
    const float* __restrict__ db = dens + ((size_t)f * NQ * NC + c) * 4;
    float* __restrict__ op = out + (((size_t)b * NF + f) * NH + y) * NW;

#pragma unroll 1
    for (int g = 0; g < 2; ++g) { // two 8-pixel groups per half-wave
        float acc[8];
#pragma unroll
        for (int j = 0; j < 8; ++j) acc[j] = 0.f;

#pragma unroll 1
        for (int qi = 0; qi < 3; ++qi) {
            // 10-float register window: pixels g*8..g*8+7, qj 0..2
            const float* wp = &xt[c][qi][(sl << 4) + (g << 3)];
            float4 wA = *(const float4*)wp;       // w0..w3  (16B-aligned)
            float4 wB = *(const float4*)(wp + 4); // w4..w7
            f2     wC = *(const f2*)(wp + 8);     // w8..w9
            const float w[10] = {wA.x, wA.y, wA.z, wA.w,
                                 wB.x, wB.y, wB.z, wB.w,
                                 wC.x, wC.y};

#pragma unroll
            for (int qj = 0; qj < 3; ++qj) {
                // q = qi*3+qj; per-lane f2 coeff loads, contiguous over c
                const float* ap = nb + (size_t)(qi * 3 + qj) * NC * 6;
                const float* bp = db + (size_t)(qi * 3 + qj) * NC * 4;
                f2 A01 = *(const f2*)ap;
                f2 A23 = *(const f2*)(ap + 2);
                f2 A45 = *(const f2*)(ap + 4);
                f2 D01 = *(const f2*)bp;
                f2 D23 = *(const f2*)(bp + 2);

#pragma unroll
                for (int j = 0; j < 8; ++j) {
                    float ww = w[j + qj]; // static index
                    float nu = fmaf(A45.y, ww, A45.x);
                    nu = fmaf(nu, ww, A23.y);
                    nu = fmaf(nu, ww, A23.x);
                    nu = fmaf(nu, ww, A01.y);
                    nu = fmaf(nu, ww, A01.x);
                    float dd = fmaf(D23.y, ww, D23.x);
                    dd = fmaf(dd, ww, D01.y);
                    dd = fmaf(dd, ww, D01.x);
                    dd *= ww;
                    float de = 1.0f + fabsf(dd);
                    acc[j] = fmaf(nu, __builtin_amdgcn_rcpf(de), acc[j]);
                }
            }
        }

        // c-sum over each 32-lane half; lane c == g*8+j stores its pixel
#pragma unroll
        for (int j = 0; j < 8; ++j) {
            float v = acc[j];
            v += __shfl_xor(v, 1);
            v += __shfl_xor(v, 2);
            v += __shfl_xor(v, 4);
            v += __shfl_xor(v, 8);
            v += __shfl_xor(v, 16);
            if (c == (g << 3) + j)
                op[(sl << 4) + (g << 3) + j] = v; // each output exactly once
        }
    }
}

extern "C" void kernel_launch(void* const* d_in, const int* in_sizes, int n_in,
                              void* d_out, int out_size, void* d_ws, size_t ws_size,
                              hipStream_t stream) {
    const float* x    = (const float*)d_in[0];
    const float* nums = (const float*)d_in[1];
    const float* dens = (const float*)d_in[2];
    float* out = (float*)d_out;

    // no memset: every output element is written by exactly one direct store
    dim3 grid(NB * NH * FSPLIT); // 2048 blocks: (b, y, f-quad) -> 8/CU
    dim3 block(256);
    ka_conv_rational_kernel<<<grid, block, 0, stream>>>(x, nums, dens, out);
}

// Round 14
// 84.211 us; speedup vs baseline: 1.1881x; 1.1881x over previous
//
#include <hip/hip_runtime.h>
#include <math.h>

// Problem constants (from reference): B=8, C=32, F=32, K=3, H=W=32
#define NB 8
#define NC 32
#define NF 32
#define NH 32
#define NW 32
#define NQ 9
#define FSPLIT 8   // f-quads per (b,y)
#define FPB 4      // f per block = ONE PER WAVE
#define TSX 37     // LDS col stride: lane-stride 37 -> 5c mod 32, gcd=1

typedef float f2 __attribute__((ext_vector_type(2)));
__device__ __forceinline__ f2 sp2(float v) { return (f2){v, v}; }

// v12: channels-on-lanes + PACKED evals + per-lane coeffs.
// Session dissection: v5 = fat stream (~30us VALU) at ~95% busy; v11 =
// lean stream (23us VALU, per-lane coeffs, scalar Horner) at 44% busy
// (90 unprefetched coeff VMEM loads/wave on the critical path). v12
// combines the lean mapping with pk-f32 packed evals (v_pk_fma_f32 on
// VGPR pairs, gfx90a+): each lane evals 2 adjacent pixels/instr, coeff
// splats via VOP3P op_sel (per-lane VGPR scalars -> no SGPR rule, no
// splat movs). w-pairs read per (qi,qj) as adjacent-dword LDS pairs
// (ds_read2_b32); LDS [3][32][37] lane-stride 37 -> conflict-free.
// unroll-1 on g/qi/qj loops prevents the v4/v9 hoist-spill (~45 live
// regs < 64 cap); static j loop only. Coeff loads: 5xf2 per qj with
// ~230cy of pk compute between sets + 8 waves/SIMD TLP. Butterfly
// c-sum + direct stores: no atomics, no out-memset.
__global__ __launch_bounds__(256, 8) void ka_conv_rational_kernel(
    const float* __restrict__ x,     // [B, C, H, W]
    const float* __restrict__ nums,  // [F*Q*C, 6]
    const float* __restrict__ dens,  // [F*Q*C, 4]
    float* __restrict__ out)         // [B, F, H, W]
{
    __shared__ float xt[3][NC][TSX]; // 14,208 B

    const int t   = threadIdx.x;
    const int bid = blockIdx.x;        // 0..2047 = (b, y, fq)
    const int fq  = bid & (FSPLIT - 1);
    const int y   = (bid >> 3) & (NH - 1);
    const int b   = bid >> 8;

    // ---- stage x[b, all c, y-1..y+1, all cols]; pads k=0 and k=33.
    // Coalesced: consecutive threads -> consecutive cols of 128B rows.
#pragma unroll
    for (int i = 0; i < 12; ++i) {
        int e   = t + i * 256;          // 3072 = 3r * 32c * 32col
        int rr  = e >> 10;
        int rem = e & 1023;
        int cc  = rem >> 5;
        int col = rem & 31;
        int gy  = y - 1 + rr;
        float v = (gy >= 0 && gy < NH)
                      ? x[(((size_t)b * NC + cc) * NH + gy) * NW + col]
                      : 0.f;
        xt[rr][cc][col + 1] = v;
    }
    if (t < 96) {
        xt[t >> 5][t & 31][0] = 0.f;
    } else if (t >= 128 && t < 224) {
        int u = t - 128;
        xt[u >> 5][u & 31][33] = 0.f;
    }
    __syncthreads(); // only barrier

    const int lane = t & 63;
    const int c    = lane & 31; // this lane's channel
    const int sl   = lane >> 5; // pixel half: cols sl*16 .. sl*16+15
    const int wv   = t >> 6;    // 0..3
    const int f    = fq * FPB + wv;

    const float* __restrict__ nb0 = nums + ((size_t)f * NQ * NC + c) * 6;
    const float* __restrict__ db0 = dens + ((size_t)f * NQ * NC + c) * 4;
    float* __restrict__ op = out + (((size_t)b * NF + f) * NH + y) * NW;

#pragma unroll 1
    for (int g = 0; g < 2; ++g) { // two 8-pixel groups (4 pairs) per half
        f2 acc[4];
#pragma unroll
        for (int j = 0; j < 4; ++j) acc[j] = (f2){0.f, 0.f};

        const int pbase = (sl << 4) + (g << 3); // first pixel col of group

        const float* ap = nb0;
        const float* bp = db0;
#pragma unroll 1
        for (int qi = 0; qi < 3; ++qi) {
            const float* row = &xt[qi][c][0];
#pragma unroll 1
            for (int qj = 0; qj < 3; ++qj) {
                // per-lane coeffs for q = qi*3+qj (f2 loads, 8B-aligned:
                // nums rows 24B, dens rows 16B; L2-hot 368KB table)
                f2 A01 = *(const f2*)(ap);
                f2 A23 = *(const f2*)(ap + 2);
                f2 A45 = *(const f2*)(ap + 4);
                f2 D01 = *(const f2*)(bp);
                f2 D23 = *(const f2*)(bp + 2);
                ap += NC * 6;
                bp += NC * 4;

                const int kb = pbase + qj; // window base (0..33 all valid)
#pragma unroll
                for (int j = 0; j < 4; ++j) {
                    // adjacent-dword LDS pair -> ds_read2_b32
                    f2 ww = {row[kb + 2 * j], row[kb + 2 * j + 1]};
                    f2 nu = __builtin_elementwise_fma(sp2(A45.y), ww, sp2(A45.x));
                    nu = __builtin_elementwise_fma(nu, ww, sp2(A23.y));
                    nu = __builtin_elementwise_fma(nu, ww, sp2(A23.x));
                    nu = __builtin_elementwise_fma(nu, ww, sp2(A01.y));
                    nu = __builtin_elementwise_fma(nu, ww, sp2(A01.x));
                    f2 dd = __builtin_elementwise_fma(sp2(D23.y), ww, sp2(D23.x));
                    dd = __builtin_elementwise_fma(dd, ww, sp2(D01.y));
                    dd = __builtin_elementwise_fma(dd, ww, sp2(D01.x));
                    dd = dd * ww;
                    f2 de = 1.0f + __builtin_elementwise_abs(dd);
                    f2 r  = {__builtin_amdgcn_rcpf(de.x),
                             __builtin_amdgcn_rcpf(de.y)};
                    acc[j] = __builtin_elementwise_fma(nu, r, acc[j]);
                }
            }
        }

        // ---- c-sum over each 32-lane half (masks <=16 stay in-half),
        // then lane c==j stores its pixel pair (each output exactly once)
#pragma unroll
        for (int j = 0; j < 4; ++j) {
            float vx = acc[j].x, vy = acc[j].y;
            vx += __shfl_xor(vx, 1);  vy += __shfl_xor(vy, 1);
            vx += __shfl_xor(vx, 2);  vy += __shfl_xor(vy, 2);
            vx += __shfl_xor(vx, 4);  vy += __shfl_xor(vy, 4);
            vx += __shfl_xor(vx, 8);  vy += __shfl_xor(vy, 8);
            vx += __shfl_xor(vx, 16); vy += __shfl_xor(vy, 16);
            if (c == j) {
                op[pbase + 2 * j]     = vx;
                op[pbase + 2 * j + 1] = vy;
            }
        }
    }
}

extern "C" void kernel_launch(void* const* d_in, const int* in_sizes, int n_in,
                              void* d_out, int out_size, void* d_ws, size_t ws_size,
                              hipStream_t stream) {
    const float* x    = (const float*)d_in[0];
    const float* nums = (const float*)d_in[1];
    const float* dens = (const float*)d_in[2];
    float* out = (float*)d_out;

    // no memset: every output element is written by exactly one direct store
    dim3 grid(NB * NH * FSPLIT); // 2048 blocks: (b, y, f-quad) -> 8/CU
    dim3 block(256);
    ka_conv_rational_kernel<<<grid, block, 0, stream>>>(x, nums, dens, out);
}

// Round 15
// 83.978 us; speedup vs baseline: 1.1914x; 1.0028x over previous
//
#include <hip/hip_runtime.h>
#include <math.h>

// Problem constants (from reference): B=8, C=32, F=32, K=3, H=W=32
#define NB 8
#define NC 32
#define NF 32
#define NH 32
#define NW 32
#define NQ 9
#define FSPLIT 8   // f-quads per (b,y)
#define FPB 4      // f per block = ONE PER WAVE
#define TSX 37     // LDS col stride: lane-stride 37 -> 5c mod 32, gcd=1

typedef float f2 __attribute__((ext_vector_type(2)));
__device__ __forceinline__ f2 sp2(float v) { return (f2){v, v}; }

// v13 = v12 with the coefficient-load economics fixed (no new structure):
//  1) g groups MERGED: one q-pass evals all 16 pixels (8 packed pairs)
//     per lane -> coeff loads halve (90->45/lane), compute per coeff
//     set doubles (~220cy).
//  2) depth-1 ROLLING COEFF PREFETCH (the v1/v5-proven pattern, first
//     time on this mapping): q+1's 5 f2 loads issue at the top of q's
//     body; ~220cy of pk compute + 8-wave TLP covers the ~200cy L2-hot
//     latency (368KB table shared by 256 blocks per f).
//  3) q-loop unroll 1 (3x-measured spill containment); all register
//     indexing static; qi/qj runtime only in ADDRESS arithmetic.
//     Live regs ~54 < the 64 cap.
// Carried from v12: channels-on-lanes (lean, no SGPR-splat fat),
// pk-f32 paired evals, [3][32][37] conflict-free LDS (2 lanes/bank =
// free, m136), butterfly c-sum + direct stores (no atomics, no memset).
__global__ __launch_bounds__(256, 8) void ka_conv_rational_kernel(
    const float* __restrict__ x,     // [B, C, H, W]
    const float* __restrict__ nums,  // [F*Q*C, 6]
    const float* __restrict__ dens,  // [F*Q*C, 4]
    float* __restrict__ out)         // [B, F, H, W]
{
    __shared__ float xt[3][NC][TSX]; // 14,208 B

    const int t   = threadIdx.x;
    const int bid = blockIdx.x;        // 0..2047 = (b, y, fq)
    const int fq  = bid & (FSPLIT - 1);
    const int y   = (bid >> 3) & (NH - 1);
    const int b   = bid >> 8;

    // ---- stage x[b, all c, y-1..y+1, all cols]; pads k=0 and k=33.
    // (verified passing in v12) ----
#pragma unroll
    for (int i = 0; i < 12; ++i) {
        int e   = t + i * 256;          // 3072 = 3r * 32c * 32col
        int rr  = e >> 10;
        int rem = e & 1023;
        int cc  = rem >> 5;
        int col = rem & 31;
        int gy  = y - 1 + rr;
        float v = (gy >= 0 && gy < NH)
                      ? x[(((size_t)b * NC + cc) * NH + gy) * NW + col]
                      : 0.f;
        xt[rr][cc][col + 1] = v;
    }
    if (t < 96) {
        xt[t >> 5][t & 31][0] = 0.f;
    } else if (t >= 128 && t < 224) {
        int u = t - 128;
        xt[u >> 5][u & 31][33] = 0.f;
    }
    __syncthreads(); // only barrier

    const int lane = t & 63;
    const int c    = lane & 31; // this lane's channel
    const int sl   = lane >> 5; // pixel half: cols sl*16 .. sl*16+15
    const int wv   = t >> 6;    // 0..3
    const int f    = fq * FPB + wv;

    const float* __restrict__ nb = nums + ((size_t)f * NQ * NC + c) * 6;
    const float* __restrict__ db = dens + ((size_t)f * NQ * NC + c) * 4;
    float* __restrict__ op = out + (((size_t)b * NF + f) * NH + y) * NW;

    const int pbase = sl << 4; // this half-wave's 16 pixel columns

    f2 acc[8];
#pragma unroll
    for (int j = 0; j < 8; ++j) acc[j] = (f2){0.f, 0.f};

    // prefetch q=0 coefficients (per-lane, contiguous over c)
    f2 nA01 = *(const f2*)(nb);
    f2 nA23 = *(const f2*)(nb + 2);
    f2 nA45 = *(const f2*)(nb + 4);
    f2 nD01 = *(const f2*)(db);
    f2 nD23 = *(const f2*)(db + 2);

#pragma unroll 1
    for (int q = 0; q < NQ; ++q) {
        // consume prefetched coeffs; issue next q's loads immediately
        const f2 A01 = nA01, A23 = nA23, A45 = nA45;
        const f2 D01 = nD01, D23 = nD23;
        if (q + 1 < NQ) {
            const float* ap = nb + (size_t)(q + 1) * NC * 6;
            const float* bp = db + (size_t)(q + 1) * NC * 4;
            nA01 = *(const f2*)ap;
            nA23 = *(const f2*)(ap + 2);
            nA45 = *(const f2*)(ap + 4);
            nD01 = *(const f2*)bp;
            nD23 = *(const f2*)(bp + 2);
        }

        const int qi = q / 3, qj = q - qi * 3; // uniform -> SALU
        const float* row = &xt[qi][c][pbase + qj];

#pragma unroll
        for (int j = 0; j < 8; ++j) {
            // adjacent-dword LDS pair (ds_read2_b32/b64), conflict-free
            f2 ww = {row[2 * j], row[2 * j + 1]};
            f2 nu = __builtin_elementwise_fma(sp2(A45.y), ww, sp2(A45.x));
            nu = __builtin_elementwise_fma(nu, ww, sp2(A23.y));
            nu = __builtin_elementwise_fma(nu, ww, sp2(A23.x));
            nu = __builtin_elementwise_fma(nu, ww, sp2(A01.y));
            nu = __builtin_elementwise_fma(nu, ww, sp2(A01.x));
            f2 dd = __builtin_elementwise_fma(sp2(D23.y), ww, sp2(D23.x));
            dd = __builtin_elementwise_fma(dd, ww, sp2(D01.y));
            dd = __builtin_elementwise_fma(dd, ww, sp2(D01.x));
            dd = dd * ww;
            f2 de = 1.0f + __builtin_elementwise_abs(dd);
            f2 r  = {__builtin_amdgcn_rcpf(de.x),
                     __builtin_amdgcn_rcpf(de.y)};
            acc[j] = __builtin_elementwise_fma(nu, r, acc[j]);
        }
    }

    // ---- c-sum over each 32-lane half (xor masks <32 stay in-half);
    // lane c==j stores its pixel pair: each output written exactly once.
#pragma unroll
    for (int j = 0; j < 8; ++j) {
        float vx = acc[j].x, vy = acc[j].y;
        vx += __shfl_xor(vx, 1);  vy += __shfl_xor(vy, 1);
        vx += __shfl_xor(vx, 2);  vy += __shfl_xor(vy, 2);
        vx += __shfl_xor(vx, 4);  vy += __shfl_xor(vy, 4);
        vx += __shfl_xor(vx, 8);  vy += __shfl_xor(vy, 8);
        vx += __shfl_xor(vx, 16); vy += __shfl_xor(vy, 16);
        if (c == j) {
            op[pbase + 2 * j]     = vx;
            op[pbase + 2 * j + 1] = vy;
        }
    }
}

extern "C" void kernel_launch(void* const* d_in, const int* in_sizes, int n_in,
                              void* d_out, int out_size, void* d_ws, size_t ws_size,
                              hipStream_t stream) {
    const float* x    = (const float*)d_in[0];
    const float* nums = (const float*)d_in[1];
    const float* dens = (const float*)d_in[2];
    float* out = (float*)d_out;

    // no memset: every output element is written by exactly one direct store
    dim3 grid(NB * NH * FSPLIT); // 2048 blocks: (b, y, f-quad) -> 8/CU
    dim3 block(256);
    ka_conv_rational_kernel<<<grid, block, 0, stream>>>(x, nums, dens, out);
}